// Round 1
// baseline (204.461 us; speedup 1.0000x reference)
//
#include <hip/hip_runtime.h>

typedef short short8v __attribute__((ext_vector_type(8)));
typedef float f32x4 __attribute__((ext_vector_type(4)));
typedef unsigned short u16;
typedef unsigned int u32;

__device__ __forceinline__ u16 f2bf(float f) {
    u32 u = __float_as_uint(f);
    u += 0x7FFFu + ((u >> 16) & 1u);   // round-to-nearest-even
    return (u16)(u >> 16);
}
__device__ __forceinline__ float bf2f(u16 h) {
    return __uint_as_float(((u32)h) << 16);
}
__device__ __forceinline__ float gelu_f(float v) {
    float u = 0.7978845608028654f * fmaf(0.044715f * v, v * v, v);
    return 0.5f * v * (1.0f + tanhf(u));
}
__device__ __forceinline__ void gload16(const void* g, void* l) {
    __builtin_amdgcn_global_load_lds(
        (const __attribute__((address_space(1))) u32*)g,
        (__attribute__((address_space(3))) u32*)l, 16, 0, 0);
}

// ---------------- K0a: cast x (f32 -> bf16), 8 elems/thread ----------------
__global__ __launch_bounds__(256) void k_cast_x(const float* __restrict__ x, u16* __restrict__ xb) {
    int idx = blockIdx.x * 256 + threadIdx.x;          // 0 .. 2097151
    const float4* in = (const float4*)x;
    float4 a = in[idx * 2], c = in[idx * 2 + 1];
    short8v s;
    s[0] = (short)f2bf(a.x); s[1] = (short)f2bf(a.y); s[2] = (short)f2bf(a.z); s[3] = (short)f2bf(a.w);
    s[4] = (short)f2bf(c.x); s[5] = (short)f2bf(c.y); s[6] = (short)f2bf(c.z); s[7] = (short)f2bf(c.w);
    *(short8v*)(xb + (size_t)idx * 8) = s;
}

// ---------------- K0b: Wt[g][o][i] = bf16(W[g][i][o]) ----------------
__global__ __launch_bounds__(1024) void k_prep_w(const float* __restrict__ w, u16* __restrict__ wt) {
    __shared__ float t[32][33];
    int g = blockIdx.z, o0 = blockIdx.x * 32, i0 = blockIdx.y * 32;
    int tx = threadIdx.x, ty = threadIdx.y;
    t[ty][tx] = w[(size_t)g * 262144 + (size_t)(i0 + ty) * 512 + (o0 + tx)];
    __syncthreads();
    wt[(size_t)g * 262144 + (size_t)(o0 + ty) * 512 + (i0 + tx)] = f2bf(t[tx][ty]);
}

// ---------------- K0c: gpt[p][f] = gp[f][p] ----------------
__global__ __launch_bounds__(256) void k_prep_gp(const float* __restrict__ gp, float* __restrict__ gpt) {
    for (int l = threadIdx.x; l < 10240; l += 256) {
        int f = l / 20, p = l % 20;
        gpt[p * 512 + f] = gp[l];
    }
}

// ---------------- K1: y = gelu(x @ W[grade] + bias), bf16 out ----------------
// M = 32768 (8 blades x 4096), N = 512, K = 512. BM=BN=128, BK=64, 4 waves (2x2).
__global__ __launch_bounds__(256) void k_gemm(const u16* __restrict__ xb, const u16* __restrict__ wt,
                                              const float* __restrict__ bias, u16* __restrict__ yb) {
    __shared__ __align__(16) u16 sA[128 * 64];
    __shared__ __align__(16) u16 sB[128 * 64];
    const int tid = threadIdx.x;
    const int w = tid >> 6, lane = tid & 63;
    const int mt = blockIdx.x, nt = blockIdx.y;
    const int WE[8] = {0, 1, 1, 1, 2, 2, 2, 3};
    const int g = WE[mt >> 5];
    const u16* Abase = xb + (size_t)mt * 128 * 512;
    const u16* Bbase = wt + (size_t)g * 262144 + (size_t)nt * 128 * 512;
    const int wr = w >> 1, wc = w & 1;

    f32x4 acc[4][4];
#pragma unroll
    for (int m = 0; m < 4; m++)
#pragma unroll
        for (int n = 0; n < 4; n++) acc[m][n] = (f32x4){0.f, 0.f, 0.f, 0.f};

    const int lr = lane >> 3;            // row within 8-row chunk
    const int lc = (lane & 7) * 16;      // byte col within 128B row
    for (int kt = 0; kt < 8; ++kt) {
#pragma unroll
        for (int p = 0; p < 4; ++p) {
            int chunk = w * 4 + p;       // 0..15, 8 rows each
            const char* ga = (const char*)(Abase + ((size_t)(chunk * 8 + lr) * 512 + kt * 64)) + lc;
            gload16(ga, (char*)sA + chunk * 1024);
            const char* gb = (const char*)(Bbase + ((size_t)(chunk * 8 + lr) * 512 + kt * 64)) + lc;
            gload16(gb, (char*)sB + chunk * 1024);
        }
        __syncthreads();
#pragma unroll
        for (int kk = 0; kk < 2; ++kk) {
            short8v af[4], bf[4];
            const int ko = kk * 64 + ((lane >> 4) * 16);   // byte offset of k in row
#pragma unroll
            for (int m = 0; m < 4; m++) {
                int row = wr * 64 + m * 16 + (lane & 15);
                af[m] = *(const short8v*)((const char*)sA + row * 128 + ko);
            }
#pragma unroll
            for (int n = 0; n < 4; n++) {
                int col = wc * 64 + n * 16 + (lane & 15);
                bf[n] = *(const short8v*)((const char*)sB + col * 128 + ko);
            }
#pragma unroll
            for (int m = 0; m < 4; m++)
#pragma unroll
                for (int n = 0; n < 4; n++)
                    acc[m][n] = __builtin_amdgcn_mfma_f32_16x16x32_bf16(af[m], bf[n], acc[m][n], 0, 0, 0);
        }
        __syncthreads();
    }

    const size_t row0 = (size_t)mt * 128 + wr * 64;
    const int colBase = nt * 128 + wc * 64;
#pragma unroll
    for (int n = 0; n < 4; n++) {
        int col = colBase + n * 16 + (lane & 15);
        float bv = bias[col];
#pragma unroll
        for (int m = 0; m < 4; m++) {
#pragma unroll
            for (int j = 0; j < 4; j++) {
                size_t row = row0 + m * 16 + (lane >> 4) * 4 + j;
                float v = acc[m][n][j] + bv;
                yb[row * 512 + col] = f2bf(gelu_f(v));
            }
        }
    }
}

// ---------------- K2: geometric product + grade RMS norm ----------------
#define TERM(i, j, k, s, p) o[ff][k] = fmaf(s * wp[ff][p], xv[ff][i] * yv[ff][j], o[ff][k]);
#define GP_ALL \
    TERM(0,0,0, 1.0f,0) TERM(0,1,1, 1.0f,1) TERM(0,2,2, 1.0f,1) TERM(0,3,3, 1.0f,1) \
    TERM(0,4,4, 1.0f,2) TERM(0,5,5, 1.0f,2) TERM(0,6,6, 1.0f,2) TERM(0,7,7, 1.0f,3) \
    TERM(1,0,1, 1.0f,4) TERM(1,1,0, 1.0f,5) TERM(1,2,4, 1.0f,6) TERM(1,3,5, 1.0f,6) \
    TERM(1,4,2, 1.0f,7) TERM(1,5,3, 1.0f,7) TERM(1,6,7, 1.0f,8) TERM(1,7,6, 1.0f,9) \
    TERM(2,0,2, 1.0f,4) TERM(2,1,4,-1.0f,6) TERM(2,2,0, 1.0f,5) TERM(2,3,6, 1.0f,6) \
    TERM(2,4,1,-1.0f,7) TERM(2,5,7,-1.0f,8) TERM(2,6,3, 1.0f,7) TERM(2,7,5,-1.0f,9) \
    TERM(3,0,3, 1.0f,4) TERM(3,1,5,-1.0f,6) TERM(3,2,6,-1.0f,6) TERM(3,3,0, 1.0f,5) \
    TERM(3,4,7, 1.0f,8) TERM(3,5,1,-1.0f,7) TERM(3,6,2,-1.0f,7) TERM(3,7,4, 1.0f,9) \
    TERM(4,0,4, 1.0f,10) TERM(4,1,2,-1.0f,11) TERM(4,2,1, 1.0f,11) TERM(4,3,7, 1.0f,12) \
    TERM(4,4,0,-1.0f,13) TERM(4,5,6,-1.0f,14) TERM(4,6,5, 1.0f,14) TERM(4,7,3,-1.0f,15) \
    TERM(5,0,5, 1.0f,10) TERM(5,1,3,-1.0f,11) TERM(5,2,7,-1.0f,12) TERM(5,3,1, 1.0f,11) \
    TERM(5,4,6, 1.0f,14) TERM(5,5,0,-1.0f,13) TERM(5,6,4,-1.0f,14) TERM(5,7,2, 1.0f,15) \
    TERM(6,0,6, 1.0f,10) TERM(6,1,7, 1.0f,12) TERM(6,2,3,-1.0f,11) TERM(6,3,2, 1.0f,11) \
    TERM(6,4,5,-1.0f,14) TERM(6,5,4, 1.0f,14) TERM(6,6,0,-1.0f,13) TERM(6,7,1,-1.0f,15) \
    TERM(7,0,7, 1.0f,16) TERM(7,1,6, 1.0f,17) TERM(7,2,5,-1.0f,17) TERM(7,3,4, 1.0f,17) \
    TERM(7,4,3,-1.0f,18) TERM(7,5,2, 1.0f,18) TERM(7,6,1,-1.0f,18) TERM(7,7,0,-1.0f,19)

__global__ __launch_bounds__(256) void k_gp(const u16* __restrict__ xb, const u16* __restrict__ yb,
                                            const float* __restrict__ gpt, float* __restrict__ out) {
    const int b = blockIdx.x, tid = threadIdx.x;
    const int w = tid >> 6, lane = tid & 63;
    const int f0 = tid * 2;

    float xv[2][8], yv[2][8], wp[2][20], o[2][8];
#pragma unroll
    for (int i = 0; i < 8; i++) {
        u32 ux = *(const u32*)(xb + ((size_t)i * 4096 + b) * 512 + f0);
        xv[0][i] = bf2f((u16)(ux & 0xFFFF)); xv[1][i] = bf2f((u16)(ux >> 16));
        u32 uy = *(const u32*)(yb + ((size_t)i * 4096 + b) * 512 + f0);
        yv[0][i] = bf2f((u16)(uy & 0xFFFF)); yv[1][i] = bf2f((u16)(uy >> 16));
    }
#pragma unroll
    for (int p = 0; p < 20; p++) {
        float2 wv = *(const float2*)(gpt + p * 512 + f0);
        wp[0][p] = wv.x; wp[1][p] = wv.y;
    }

    float ss[4] = {0.f, 0.f, 0.f, 0.f};
#pragma unroll
    for (int ff = 0; ff < 2; ++ff) {
#pragma unroll
        for (int k = 0; k < 8; k++) o[ff][k] = 0.f;
        GP_ALL
        ss[0] += o[ff][0] * o[ff][0];
        ss[1] += o[ff][1] * o[ff][1] + o[ff][2] * o[ff][2] + o[ff][3] * o[ff][3];
        ss[2] += o[ff][4] * o[ff][4] + o[ff][5] * o[ff][5] + o[ff][6] * o[ff][6];
        ss[3] += o[ff][7] * o[ff][7];
    }

#pragma unroll
    for (int g2 = 0; g2 < 4; g2++) {
        float v = ss[g2];
#pragma unroll
        for (int off = 32; off >= 1; off >>= 1) v += __shfl_xor(v, off);
        ss[g2] = v;
    }
    __shared__ float red[4][4];
    if (lane == 0) { red[w][0] = ss[0]; red[w][1] = ss[1]; red[w][2] = ss[2]; red[w][3] = ss[3]; }
    __syncthreads();
    float inv[4];
    const float cnt[4] = {512.f, 1536.f, 1536.f, 512.f};
#pragma unroll
    for (int g2 = 0; g2 < 4; g2++) {
        float tot = red[0][g2] + red[1][g2] + red[2][g2] + red[3][g2];
        inv[g2] = 1.0f / sqrtf(tot / cnt[g2] + 1e-6f);
    }
    const int GK[8] = {0, 1, 1, 1, 2, 2, 2, 3};
#pragma unroll
    for (int k = 0; k < 8; k++) {
        float2 st;
        st.x = o[0][k] * inv[GK[k]];
        st.y = o[1][k] * inv[GK[k]];
        *(float2*)(out + ((size_t)k * 4096 + b) * 512 + f0) = st;
    }
}

extern "C" void kernel_launch(void* const* d_in, const int* in_sizes, int n_in,
                              void* d_out, int out_size, void* d_ws, size_t ws_size,
                              hipStream_t stream) {
    const float* x  = (const float*)d_in[0];
    const float* lw = (const float*)d_in[1];
    const float* lb = (const float*)d_in[2];
    const float* gp = (const float*)d_in[3];
    float* out = (float*)d_out;
    char* ws = (char*)d_ws;
    u16*   xb  = (u16*)ws;                        // 33,554,432 B
    u16*   wt  = (u16*)(ws + 33554432);           //  2,097,152 B
    float* gpt = (float*)(ws + 35651584);         //     40,960 B
    u16*   yb  = (u16*)(ws + 35692544);           // 33,554,432 B  (total ~69.2 MB)

    hipLaunchKernelGGL(k_cast_x, dim3(8192), dim3(256), 0, stream, x, xb);
    hipLaunchKernelGGL(k_prep_w, dim3(16, 16, 4), dim3(32, 32), 0, stream, lw, wt);
    hipLaunchKernelGGL(k_prep_gp, dim3(1), dim3(256), 0, stream, gp, gpt);
    hipLaunchKernelGGL(k_gemm, dim3(256, 4), dim3(256), 0, stream, xb, wt, lb, yb);
    hipLaunchKernelGGL(k_gp, dim3(4096), dim3(256), 0, stream, xb, yb, gpt, out);
}

// Round 3
// 197.680 us; speedup vs baseline: 1.0343x; 1.0343x over previous
//
#include <hip/hip_runtime.h>

typedef short short8v __attribute__((ext_vector_type(8)));
typedef float f32x4 __attribute__((ext_vector_type(4)));
typedef unsigned short u16;
typedef unsigned int u32;

__device__ __forceinline__ u16 f2bf(float f) {
    u32 u = __float_as_uint(f);
    u += 0x7FFFu + ((u >> 16) & 1u);   // round-to-nearest-even
    return (u16)(u >> 16);
}
__device__ __forceinline__ float bf2f(u16 h) {
    return __uint_as_float(((u32)h) << 16);
}
__device__ __forceinline__ float gelu_f(float v) {
    float u = 0.7978845608028654f * fmaf(0.044715f * v, v * v, v);
    return 0.5f * v * (1.0f + tanhf(u));
}
__device__ __forceinline__ void gload16(const void* g, void* l) {
    __builtin_amdgcn_global_load_lds(
        (const __attribute__((address_space(1))) u32*)g,
        (__attribute__((address_space(3))) u32*)l, 16, 0, 0);
}

// ---------------- K0: fused prep: cast x (blocks 0..8191) + W transpose (blocks 8192..9215) ----
__global__ __launch_bounds__(256) void k_prep(const float* __restrict__ x, u16* __restrict__ xb,
                                              const float* __restrict__ w, u16* __restrict__ wt) {
    const int bid = blockIdx.x, tid = threadIdx.x;
    if (bid < 8192) {
        int idx = bid * 256 + tid;                     // 0 .. 2097151
        const float4* in = (const float4*)x;
        float4 a = in[idx * 2], c = in[idx * 2 + 1];
        short8v s;
        s[0] = (short)f2bf(a.x); s[1] = (short)f2bf(a.y); s[2] = (short)f2bf(a.z); s[3] = (short)f2bf(a.w);
        s[4] = (short)f2bf(c.x); s[5] = (short)f2bf(c.y); s[6] = (short)f2bf(c.z); s[7] = (short)f2bf(c.w);
        *(short8v*)(xb + (size_t)idx * 8) = s;
    } else {
        __shared__ float t[32][33];
        int tb = bid - 8192;
        int g = tb >> 8, rem = tb & 255;
        int o0 = (rem & 15) * 32, i0 = (rem >> 4) * 32;
        int tx = tid & 31, ty4 = tid >> 5;             // ty4: 0..7, 4 rows each
#pragma unroll
        for (int r = 0; r < 4; r++) {
            int ty = ty4 * 4 + r;
            t[ty][tx] = w[(size_t)g * 262144 + (size_t)(i0 + ty) * 512 + (o0 + tx)];
        }
        __syncthreads();
#pragma unroll
        for (int r = 0; r < 4; r++) {
            int ty = ty4 * 4 + r;
            wt[(size_t)g * 262144 + (size_t)(o0 + ty) * 512 + (i0 + tx)] = f2bf(t[tx][ty]);
        }
    }
}

// ---------------- K1: y = gelu(x @ W[grade] + bias), bf16 out ----------------
// M = 32768 (8 blades x 4096), N = 512, K = 512. BM=BN=128, BK=64, 4 waves (2x2).
// Double-buffered LDS with prefetch: STAGE(t+1) issued BEFORE compute(t); one barrier/tile.
__global__ __launch_bounds__(256) void k_gemm(const u16* __restrict__ xb, const u16* __restrict__ wt,
                                              const float* __restrict__ bias, u16* __restrict__ yb) {
    __shared__ __align__(16) u16 sA[2][128 * 64];
    __shared__ __align__(16) u16 sB[2][128 * 64];
    const int tid = threadIdx.x;
    const int w = tid >> 6, lane = tid & 63;
    // XCD-chunked bijective swizzle (1024 blocks, 1024 % 8 == 0)
    const int bid = blockIdx.x;
    const int swz = (bid & 7) * 128 + (bid >> 3);
    const int mt = swz >> 2, nt = swz & 3;
    const int WE[8] = {0, 1, 1, 1, 2, 2, 2, 3};
    const int g = WE[mt >> 5];
    const u16* Abase = xb + (size_t)mt * 128 * 512;
    const u16* Bbase = wt + (size_t)g * 262144 + (size_t)nt * 128 * 512;
    const int wr = w >> 1, wc = w & 1;
    const int lr = lane >> 3;            // row within 8-row chunk
    const int lc = (lane & 7) * 16;      // byte col within 128B row

    f32x4 acc[4][4];
#pragma unroll
    for (int m = 0; m < 4; m++)
#pragma unroll
        for (int n = 0; n < 4; n++) acc[m][n] = (f32x4){0.f, 0.f, 0.f, 0.f};

#define STAGE(BUF, KT) { \
    _Pragma("unroll") \
    for (int p = 0; p < 4; ++p) { \
        int chunk = w * 4 + p; \
        gload16((const char*)(Abase + ((size_t)(chunk * 8 + lr) * 512 + (KT) * 64)) + lc, \
                (char*)sA[BUF] + chunk * 1024); \
        gload16((const char*)(Bbase + ((size_t)(chunk * 8 + lr) * 512 + (KT) * 64)) + lc, \
                (char*)sB[BUF] + chunk * 1024); \
    } }

#define COMPUTE(BUF) { \
    _Pragma("unroll") \
    for (int kk = 0; kk < 2; ++kk) { \
        short8v af[4], bfr[4]; \
        const int ko = kk * 64 + ((lane >> 4) * 16); \
        _Pragma("unroll") \
        for (int m = 0; m < 4; m++) { \
            int row = wr * 64 + m * 16 + (lane & 15); \
            af[m] = *(const short8v*)((const char*)sA[BUF] + row * 128 + ko); \
        } \
        _Pragma("unroll") \
        for (int n = 0; n < 4; n++) { \
            int col = wc * 64 + n * 16 + (lane & 15); \
            bfr[n] = *(const short8v*)((const char*)sB[BUF] + col * 128 + ko); \
        } \
        _Pragma("unroll") \
        for (int m = 0; m < 4; m++) \
            _Pragma("unroll") \
            for (int n = 0; n < 4; n++) \
                acc[m][n] = __builtin_amdgcn_mfma_f32_16x16x32_bf16(af[m], bfr[n], acc[m][n], 0, 0, 0); \
    } }

    STAGE(0, 0);
    __syncthreads();                      // compiler emits vmcnt(0) drain before s_barrier
    for (int kt = 0; kt < 6; kt += 2) {   // K-steps 0..7
        STAGE(1, kt + 1);
        COMPUTE(0);
        __syncthreads();
        STAGE(0, kt + 2);
        COMPUTE(1);
        __syncthreads();
    }
    STAGE(1, 7);
    COMPUTE(0);
    __syncthreads();
    COMPUTE(1);
#undef STAGE
#undef COMPUTE

    const size_t row0 = (size_t)mt * 128 + wr * 64;
    const int colBase = nt * 128 + wc * 64;
#pragma unroll
    for (int n = 0; n < 4; n++) {
        int col = colBase + n * 16 + (lane & 15);
        float bv = bias[col];
#pragma unroll
        for (int m = 0; m < 4; m++) {
#pragma unroll
            for (int j = 0; j < 4; j++) {
                size_t row = row0 + m * 16 + (lane >> 4) * 4 + j;
                float v = acc[m][n][j] + bv;
                yb[row * 512 + col] = f2bf(gelu_f(v));
            }
        }
    }
}

// ---------------- K2: geometric product + grade RMS norm ----------------
#define TERM(i, j, k, s, p) o[ff][k] = fmaf(s * wp[ff][p], xv[ff][i] * yv[ff][j], o[ff][k]);
#define GP_ALL \
    TERM(0,0,0, 1.0f,0) TERM(0,1,1, 1.0f,1) TERM(0,2,2, 1.0f,1) TERM(0,3,3, 1.0f,1) \
    TERM(0,4,4, 1.0f,2) TERM(0,5,5, 1.0f,2) TERM(0,6,6, 1.0f,2) TERM(0,7,7, 1.0f,3) \
    TERM(1,0,1, 1.0f,4) TERM(1,1,0, 1.0f,5) TERM(1,2,4, 1.0f,6) TERM(1,3,5, 1.0f,6) \
    TERM(1,4,2, 1.0f,7) TERM(1,5,3, 1.0f,7) TERM(1,6,7, 1.0f,8) TERM(1,7,6, 1.0f,9) \
    TERM(2,0,2, 1.0f,4) TERM(2,1,4,-1.0f,6) TERM(2,2,0, 1.0f,5) TERM(2,3,6, 1.0f,6) \
    TERM(2,4,1,-1.0f,7) TERM(2,5,7,-1.0f,8) TERM(2,6,3, 1.0f,7) TERM(2,7,5,-1.0f,9) \
    TERM(3,0,3, 1.0f,4) TERM(3,1,5,-1.0f,6) TERM(3,2,6,-1.0f,6) TERM(3,3,0, 1.0f,5) \
    TERM(3,4,7, 1.0f,8) TERM(3,5,1,-1.0f,7) TERM(3,6,2,-1.0f,7) TERM(3,7,4, 1.0f,9) \
    TERM(4,0,4, 1.0f,10) TERM(4,1,2,-1.0f,11) TERM(4,2,1, 1.0f,11) TERM(4,3,7, 1.0f,12) \
    TERM(4,4,0,-1.0f,13) TERM(4,5,6,-1.0f,14) TERM(4,6,5, 1.0f,14) TERM(4,7,3,-1.0f,15) \
    TERM(5,0,5, 1.0f,10) TERM(5,1,3,-1.0f,11) TERM(5,2,7,-1.0f,12) TERM(5,3,1, 1.0f,11) \
    TERM(5,4,6, 1.0f,14) TERM(5,5,0,-1.0f,13) TERM(5,6,4,-1.0f,14) TERM(5,7,2, 1.0f,15) \
    TERM(6,0,6, 1.0f,10) TERM(6,1,7, 1.0f,12) TERM(6,2,3,-1.0f,11) TERM(6,3,2, 1.0f,11) \
    TERM(6,4,5,-1.0f,14) TERM(6,5,4, 1.0f,14) TERM(6,6,0,-1.0f,13) TERM(6,7,1,-1.0f,15) \
    TERM(7,0,7, 1.0f,16) TERM(7,1,6, 1.0f,17) TERM(7,2,5,-1.0f,17) TERM(7,3,4, 1.0f,17) \
    TERM(7,4,3,-1.0f,18) TERM(7,5,2, 1.0f,18) TERM(7,6,1,-1.0f,18) TERM(7,7,0,-1.0f,19)

__global__ __launch_bounds__(256) void k_gp(const u16* __restrict__ xb, const u16* __restrict__ yb,
                                            const float* __restrict__ gp, float* __restrict__ out) {
    const int b = blockIdx.x, tid = threadIdx.x;
    const int w = tid >> 6, lane = tid & 63;
    const int f0 = tid * 2;

    float xv[2][8], yv[2][8], wp[2][20], o[2][8];
#pragma unroll
    for (int i = 0; i < 8; i++) {
        u32 ux = *(const u32*)(xb + ((size_t)i * 4096 + b) * 512 + f0);
        xv[0][i] = bf2f((u16)(ux & 0xFFFF)); xv[1][i] = bf2f((u16)(ux >> 16));
        u32 uy = *(const u32*)(yb + ((size_t)i * 4096 + b) * 512 + f0);
        yv[0][i] = bf2f((u16)(uy & 0xFFFF)); yv[1][i] = bf2f((u16)(uy >> 16));
    }
    // gp is [512][20] row-major; rows are 80 B -> 16B-aligned for every f (80 % 16 == 0)
#pragma unroll
    for (int ff = 0; ff < 2; ++ff) {
        const float4* gv = (const float4*)(gp + (size_t)(f0 + ff) * 20);
#pragma unroll
        for (int q = 0; q < 5; ++q) {
            float4 v = gv[q];
            wp[ff][q * 4 + 0] = v.x; wp[ff][q * 4 + 1] = v.y;
            wp[ff][q * 4 + 2] = v.z; wp[ff][q * 4 + 3] = v.w;
        }
    }

    float ss[4] = {0.f, 0.f, 0.f, 0.f};
#pragma unroll
    for (int ff = 0; ff < 2; ++ff) {
#pragma unroll
        for (int k = 0; k < 8; k++) o[ff][k] = 0.f;
        GP_ALL
        ss[0] += o[ff][0] * o[ff][0];
        ss[1] += o[ff][1] * o[ff][1] + o[ff][2] * o[ff][2] + o[ff][3] * o[ff][3];
        ss[2] += o[ff][4] * o[ff][4] + o[ff][5] * o[ff][5] + o[ff][6] * o[ff][6];
        ss[3] += o[ff][7] * o[ff][7];
    }

#pragma unroll
    for (int g2 = 0; g2 < 4; g2++) {
        float v = ss[g2];
#pragma unroll
        for (int off = 32; off >= 1; off >>= 1) v += __shfl_xor(v, off);
        ss[g2] = v;
    }
    __shared__ float red[4][4];
    if (lane == 0) { red[w][0] = ss[0]; red[w][1] = ss[1]; red[w][2] = ss[2]; red[w][3] = ss[3]; }
    __syncthreads();
    float inv[4];
    const float cnt[4] = {512.f, 1536.f, 1536.f, 512.f};
#pragma unroll
    for (int g2 = 0; g2 < 4; g2++) {
        float tot = red[0][g2] + red[1][g2] + red[2][g2] + red[3][g2];
        inv[g2] = 1.0f / sqrtf(tot / cnt[g2] + 1e-6f);
    }
    const int GK[8] = {0, 1, 1, 1, 2, 2, 2, 3};
#pragma unroll
    for (int k = 0; k < 8; k++) {
        float2 st;
        st.x = o[0][k] * inv[GK[k]];
        st.y = o[1][k] * inv[GK[k]];
        *(float2*)(out + ((size_t)k * 4096 + b) * 512 + f0) = st;
    }
}

extern "C" void kernel_launch(void* const* d_in, const int* in_sizes, int n_in,
                              void* d_out, int out_size, void* d_ws, size_t ws_size,
                              hipStream_t stream) {
    const float* x  = (const float*)d_in[0];
    const float* lw = (const float*)d_in[1];
    const float* lb = (const float*)d_in[2];
    const float* gp = (const float*)d_in[3];
    float* out = (float*)d_out;
    char* ws = (char*)d_ws;
    u16* xb = (u16*)ws;                        // 33,554,432 B
    u16* wt = (u16*)(ws + 33554432);           //  2,097,152 B
    u16* yb = (u16*)(ws + 35651584);           // 33,554,432 B

    hipLaunchKernelGGL(k_prep, dim3(9216), dim3(256), 0, stream, x, xb, lw, wt);
    hipLaunchKernelGGL(k_gemm, dim3(1024), dim3(256), 0, stream, xb, wt, lb, yb);
    hipLaunchKernelGGL(k_gp, dim3(4096), dim3(256), 0, stream, xb, yb, gp, out);
}

// Round 4
// 193.779 us; speedup vs baseline: 1.0551x; 1.0201x over previous
//
#include <hip/hip_runtime.h>

typedef short short8v __attribute__((ext_vector_type(8)));
typedef float f32x4 __attribute__((ext_vector_type(4)));
typedef unsigned short u16;
typedef unsigned int u32;

__device__ __forceinline__ u16 f2bf(float f) {
    u32 u = __float_as_uint(f);
    u += 0x7FFFu + ((u >> 16) & 1u);   // round-to-nearest-even
    return (u16)(u >> 16);
}
__device__ __forceinline__ float bf2f(u16 h) {
    return __uint_as_float(((u32)h) << 16);
}
__device__ __forceinline__ float gelu_f(float v) {
    float u = 0.7978845608028654f * fmaf(0.044715f * v, v * v, v);
    return 0.5f * v * (1.0f + tanhf(u));
}
__device__ __forceinline__ void gload16(const void* g, void* l) {
    __builtin_amdgcn_global_load_lds(
        (const __attribute__((address_space(1))) u32*)g,
        (__attribute__((address_space(3))) u32*)l, 16, 0, 0);
}

// ---------------- K0: fused prep: cast x (blocks 0..8191) + W transpose (blocks 8192..9215) ----
__global__ __launch_bounds__(256) void k_prep(const float* __restrict__ x, u16* __restrict__ xb,
                                              const float* __restrict__ w, u16* __restrict__ wt) {
    const int bid = blockIdx.x, tid = threadIdx.x;
    if (bid < 8192) {
        int idx = bid * 256 + tid;                     // 0 .. 2097151
        const float4* in = (const float4*)x;
        float4 a = in[idx * 2], c = in[idx * 2 + 1];
        short8v s;
        s[0] = (short)f2bf(a.x); s[1] = (short)f2bf(a.y); s[2] = (short)f2bf(a.z); s[3] = (short)f2bf(a.w);
        s[4] = (short)f2bf(c.x); s[5] = (short)f2bf(c.y); s[6] = (short)f2bf(c.z); s[7] = (short)f2bf(c.w);
        *(short8v*)(xb + (size_t)idx * 8) = s;
    } else {
        __shared__ float t[32][33];
        int tb = bid - 8192;
        int g = tb >> 8, rem = tb & 255;
        int o0 = (rem & 15) * 32, i0 = (rem >> 4) * 32;
        int tx = tid & 31, ty4 = tid >> 5;             // ty4: 0..7, 4 rows each
#pragma unroll
        for (int r = 0; r < 4; r++) {
            int ty = ty4 * 4 + r;
            t[ty][tx] = w[(size_t)g * 262144 + (size_t)(i0 + ty) * 512 + (o0 + tx)];
        }
        __syncthreads();
#pragma unroll
        for (int r = 0; r < 4; r++) {
            int ty = ty4 * 4 + r;
            wt[(size_t)g * 262144 + (size_t)(o0 + ty) * 512 + (i0 + tx)] = f2bf(t[tx][ty]);
        }
    }
}

// ---------------- K1: y = gelu(x @ W[grade] + bias), bf16 out ----------------
// M = 32768 (8 blades x 4096), N = 512, K = 512.
// BM=BN=256, BK=32, 512 threads (8 waves, 2x4), double-buffered LDS (64 KB total),
// 2-phase prefetch: STAGE(t+1) before COMPUTE(t), one barrier per K-step.
__global__ __launch_bounds__(512, 2) void k_gemm(const u16* __restrict__ xb, const u16* __restrict__ wt,
                                                 const float* __restrict__ bias, u16* __restrict__ yb) {
    __shared__ __align__(16) u16 sA[2][256 * 32];   // 2 x 16 KB
    __shared__ __align__(16) u16 sB[2][256 * 32];   // 2 x 16 KB
    const int tid = threadIdx.x;
    const int w = tid >> 6, lane = tid & 63;
    const int mt = blockIdx.x, nt = blockIdx.y;      // 128 x 2 tiles
    const int WE[8] = {0, 1, 1, 1, 2, 2, 2, 3};
    const int g = WE[mt >> 4];                       // 4096 rows/blade = 16 tiles of 256
    const char* Abase = (const char*)xb + (size_t)mt * 262144;                    // 256 rows x 1024 B
    const char* Bbase = (const char*)wt + (size_t)g * 524288 + (size_t)nt * 262144;
    const int wr = w >> 2, wc = w & 3;               // 2 x 4 wave grid; per-wave out 128x64

    f32x4 acc[8][4];
#pragma unroll
    for (int m = 0; m < 8; m++)
#pragma unroll
        for (int n = 0; n < 4; n++) acc[m][n] = (f32x4){0.f, 0.f, 0.f, 0.f};

    // Staging: tile row = cid>>2 (0..255), 16B chunk = cid&3; LDS dest linear (wave-uniform + lane*16).
#define STAGE(BUF, KT) { \
    _Pragma("unroll") \
    for (int q = 0; q < 2; ++q) { \
        int cid = q * 512 + tid; \
        size_t goff = (size_t)(cid >> 2) * 1024 + (KT) * 64 + (cid & 3) * 16; \
        gload16(Abase + goff, (char*)sA[BUF] + cid * 16); \
        gload16(Bbase + goff, (char*)sB[BUF] + cid * 16); \
    } }

#define COMPUTE(BUF) { \
    short8v af[8], bfr[4]; \
    const int ko = (lane >> 4) * 16; \
    _Pragma("unroll") \
    for (int m = 0; m < 8; m++) { \
        int row = wr * 128 + m * 16 + (lane & 15); \
        af[m] = *(const short8v*)((const char*)sA[BUF] + row * 64 + ko); \
    } \
    _Pragma("unroll") \
    for (int n = 0; n < 4; n++) { \
        int col = wc * 64 + n * 16 + (lane & 15); \
        bfr[n] = *(const short8v*)((const char*)sB[BUF] + col * 64 + ko); \
    } \
    _Pragma("unroll") \
    for (int m = 0; m < 8; m++) \
        _Pragma("unroll") \
        for (int n = 0; n < 4; n++) \
            acc[m][n] = __builtin_amdgcn_mfma_f32_16x16x32_bf16(af[m], bfr[n], acc[m][n], 0, 0, 0); \
    }

    STAGE(0, 0);
    __syncthreads();
    for (int kt = 0; kt < 14; kt += 2) {   // 16 K-steps of 32
        STAGE(1, kt + 1);
        COMPUTE(0);
        __syncthreads();
        STAGE(0, kt + 2);
        COMPUTE(1);
        __syncthreads();
    }
    STAGE(1, 15);
    COMPUTE(0);
    __syncthreads();
    COMPUTE(1);
#undef STAGE
#undef COMPUTE

    const size_t row0 = (size_t)mt * 256 + wr * 128;
    const int colBase = nt * 256 + wc * 64;
#pragma unroll
    for (int n = 0; n < 4; n++) {
        int col = colBase + n * 16 + (lane & 15);
        float bv = bias[col];
#pragma unroll
        for (int m = 0; m < 8; m++) {
#pragma unroll
            for (int j = 0; j < 4; j++) {
                size_t row = row0 + m * 16 + (lane >> 4) * 4 + j;
                float v = acc[m][n][j] + bv;
                yb[row * 512 + col] = f2bf(gelu_f(v));
            }
        }
    }
}

// ---------------- K2: geometric product + grade RMS norm ----------------
#define TERM(i, j, k, s, p) o[ff][k] = fmaf(s * wp[ff][p], xv[ff][i] * yv[ff][j], o[ff][k]);
#define GP_ALL \
    TERM(0,0,0, 1.0f,0) TERM(0,1,1, 1.0f,1) TERM(0,2,2, 1.0f,1) TERM(0,3,3, 1.0f,1) \
    TERM(0,4,4, 1.0f,2) TERM(0,5,5, 1.0f,2) TERM(0,6,6, 1.0f,2) TERM(0,7,7, 1.0f,3) \
    TERM(1,0,1, 1.0f,4) TERM(1,1,0, 1.0f,5) TERM(1,2,4, 1.0f,6) TERM(1,3,5, 1.0f,6) \
    TERM(1,4,2, 1.0f,7) TERM(1,5,3, 1.0f,7) TERM(1,6,7, 1.0f,8) TERM(1,7,6, 1.0f,9) \
    TERM(2,0,2, 1.0f,4) TERM(2,1,4,-1.0f,6) TERM(2,2,0, 1.0f,5) TERM(2,3,6, 1.0f,6) \
    TERM(2,4,1,-1.0f,7) TERM(2,5,7,-1.0f,8) TERM(2,6,3, 1.0f,7) TERM(2,7,5,-1.0f,9) \
    TERM(3,0,3, 1.0f,4) TERM(3,1,5,-1.0f,6) TERM(3,2,6,-1.0f,6) TERM(3,3,0, 1.0f,5) \
    TERM(3,4,7, 1.0f,8) TERM(3,5,1,-1.0f,7) TERM(3,6,2,-1.0f,7) TERM(3,7,4, 1.0f,9) \
    TERM(4,0,4, 1.0f,10) TERM(4,1,2,-1.0f,11) TERM(4,2,1, 1.0f,11) TERM(4,3,7, 1.0f,12) \
    TERM(4,4,0,-1.0f,13) TERM(4,5,6,-1.0f,14) TERM(4,6,5, 1.0f,14) TERM(4,7,3,-1.0f,15) \
    TERM(5,0,5, 1.0f,10) TERM(5,1,3,-1.0f,11) TERM(5,2,7,-1.0f,12) TERM(5,3,1, 1.0f,11) \
    TERM(5,4,6, 1.0f,14) TERM(5,5,0,-1.0f,13) TERM(5,6,4,-1.0f,14) TERM(5,7,2, 1.0f,15) \
    TERM(6,0,6, 1.0f,10) TERM(6,1,7, 1.0f,12) TERM(6,2,3,-1.0f,11) TERM(6,3,2, 1.0f,11) \
    TERM(6,4,5,-1.0f,14) TERM(6,5,4, 1.0f,14) TERM(6,6,0,-1.0f,13) TERM(6,7,1,-1.0f,15) \
    TERM(7,0,7, 1.0f,16) TERM(7,1,6, 1.0f,17) TERM(7,2,5,-1.0f,17) TERM(7,3,4, 1.0f,17) \
    TERM(7,4,3,-1.0f,18) TERM(7,5,2, 1.0f,18) TERM(7,6,1,-1.0f,18) TERM(7,7,0,-1.0f,19)

__global__ __launch_bounds__(256) void k_gp(const u16* __restrict__ xb, const u16* __restrict__ yb,
                                            const float* __restrict__ gp, float* __restrict__ out) {
    const int b = blockIdx.x, tid = threadIdx.x;
    const int w = tid >> 6, lane = tid & 63;
    const int f0 = tid * 2;

    float xv[2][8], yv[2][8], wp[2][20], o[2][8];
#pragma unroll
    for (int i = 0; i < 8; i++) {
        u32 ux = *(const u32*)(xb + ((size_t)i * 4096 + b) * 512 + f0);
        xv[0][i] = bf2f((u16)(ux & 0xFFFF)); xv[1][i] = bf2f((u16)(ux >> 16));
        u32 uy = *(const u32*)(yb + ((size_t)i * 4096 + b) * 512 + f0);
        yv[0][i] = bf2f((u16)(uy & 0xFFFF)); yv[1][i] = bf2f((u16)(uy >> 16));
    }
    // gp is [512][20] row-major; rows are 80 B -> 16B-aligned for every f (80 % 16 == 0)
#pragma unroll
    for (int ff = 0; ff < 2; ++ff) {
        const float4* gv = (const float4*)(gp + (size_t)(f0 + ff) * 20);
#pragma unroll
        for (int q = 0; q < 5; ++q) {
            float4 v = gv[q];
            wp[ff][q * 4 + 0] = v.x; wp[ff][q * 4 + 1] = v.y;
            wp[ff][q * 4 + 2] = v.z; wp[ff][q * 4 + 3] = v.w;
        }
    }

    float ss[4] = {0.f, 0.f, 0.f, 0.f};
#pragma unroll
    for (int ff = 0; ff < 2; ++ff) {
#pragma unroll
        for (int k = 0; k < 8; k++) o[ff][k] = 0.f;
        GP_ALL
        ss[0] += o[ff][0] * o[ff][0];
        ss[1] += o[ff][1] * o[ff][1] + o[ff][2] * o[ff][2] + o[ff][3] * o[ff][3];
        ss[2] += o[ff][4] * o[ff][4] + o[ff][5] * o[ff][5] + o[ff][6] * o[ff][6];
        ss[3] += o[ff][7] * o[ff][7];
    }

#pragma unroll
    for (int g2 = 0; g2 < 4; g2++) {
        float v = ss[g2];
#pragma unroll
        for (int off = 32; off >= 1; off >>= 1) v += __shfl_xor(v, off);
        ss[g2] = v;
    }
    __shared__ float red[4][4];
    if (lane == 0) { red[w][0] = ss[0]; red[w][1] = ss[1]; red[w][2] = ss[2]; red[w][3] = ss[3]; }
    __syncthreads();
    float inv[4];
    const float cnt[4] = {512.f, 1536.f, 1536.f, 512.f};
#pragma unroll
    for (int g2 = 0; g2 < 4; g2++) {
        float tot = red[0][g2] + red[1][g2] + red[2][g2] + red[3][g2];
        inv[g2] = 1.0f / sqrtf(tot / cnt[g2] + 1e-6f);
    }
    const int GK[8] = {0, 1, 1, 1, 2, 2, 2, 3};
#pragma unroll
    for (int k = 0; k < 8; k++) {
        float2 st;
        st.x = o[0][k] * inv[GK[k]];
        st.y = o[1][k] * inv[GK[k]];
        *(float2*)(out + ((size_t)k * 4096 + b) * 512 + f0) = st;
    }
}

extern "C" void kernel_launch(void* const* d_in, const int* in_sizes, int n_in,
                              void* d_out, int out_size, void* d_ws, size_t ws_size,
                              hipStream_t stream) {
    const float* x  = (const float*)d_in[0];
    const float* lw = (const float*)d_in[1];
    const float* lb = (const float*)d_in[2];
    const float* gp = (const float*)d_in[3];
    float* out = (float*)d_out;
    char* ws = (char*)d_ws;
    u16* xb = (u16*)ws;                        // 33,554,432 B
    u16* wt = (u16*)(ws + 33554432);           //  2,097,152 B
    u16* yb = (u16*)(ws + 35651584);           // 33,554,432 B

    hipLaunchKernelGGL(k_prep, dim3(9216), dim3(256), 0, stream, x, xb, lw, wt);
    hipLaunchKernelGGL(k_gemm, dim3(128, 2), dim3(512), 0, stream, xb, wt, lb, yb);
    hipLaunchKernelGGL(k_gp, dim3(4096), dim3(256), 0, stream, xb, yb, gp, out);
}